// Round 11
// baseline (282.026 us; speedup 1.0000x reference)
//
#include <hip/hip_runtime.h>
#include <hip/hip_bf16.h>

#define N_NODES 50000
#define N_EDGES 800000
#define NUM_GRAPHS 512
#define D 64
#define BN_EPS 1e-5f

#define BUK_SHIFT 7
#define BUK_SIZE 128
#define NBUK ((N_NODES + BUK_SIZE - 1) / BUK_SIZE)   // 391
#define CHUNK_A 4096
#define NBLK_A ((N_EDGES + CHUNK_A - 1) / CHUNK_A)   // 196
#define GBLK ((N_NODES + 63) / 64)                   // 782

// ---------------- bucket histogram (LDS-reduced) ----------------
__global__ __launch_bounds__(256) void k_bhist(const int* __restrict__ ei,
                                               int* __restrict__ bcnt) {
    __shared__ int h[NBUK];
    int t = threadIdx.x;
    for (int j = t; j < NBUK; j += 256) h[j] = 0;
    __syncthreads();
    int e0 = blockIdx.x * CHUNK_A;
#pragma unroll
    for (int i = 0; i < CHUNK_A / 256; i++) {
        int e = e0 + i * 256 + t;
        if (e < N_EDGES) atomicAdd(&h[ei[N_EDGES + e] >> BUK_SHIFT], 1);
    }
    __syncthreads();
    for (int j = t; j < NBUK; j += 256)
        if (h[j]) atomicAdd(&bcnt[j], h[j]);
}

// ---------------- exclusive scan of 391 bucket counts (+offs tail) ----------------
__global__ __launch_bounds__(512) void k_bscan(const int* __restrict__ bcnt,
                                               int* __restrict__ boffs,
                                               int* __restrict__ gcur,
                                               int* __restrict__ offs) {
    __shared__ int sm[512];
    int t = threadIdx.x;
    int v = (t < NBUK) ? bcnt[t] : 0;
    sm[t] = v;
    __syncthreads();
    for (int off = 1; off < 512; off <<= 1) {
        int a = sm[t];
        int u = (t >= off) ? sm[t - off] : 0;
        __syncthreads();
        sm[t] = a + u;
        __syncthreads();
    }
    if (t < NBUK) { int ex = sm[t] - v; boffs[t] = ex; gcur[t] = ex; }
    if (t == 0) { boffs[NBUK] = N_EDGES; offs[N_NODES] = N_EDGES; }
}

// ---------------- pass A: bin edges into buckets, packed u32 (row<<16 | src) ----------------
__global__ __launch_bounds__(256) void k_binA(const int* __restrict__ ei,
                                              int* __restrict__ gcur,
                                              unsigned* __restrict__ pairs) {
    __shared__ int cnt[NBUK];
    __shared__ int base[NBUK];
    int t = threadIdx.x;
    for (int j = t; j < NBUK; j += 256) cnt[j] = 0;
    __syncthreads();
    int e0 = blockIdx.x * CHUNK_A;
    unsigned pd[CHUNK_A / 256];
    int loc[CHUNK_A / 256];
#pragma unroll
    for (int i = 0; i < CHUNK_A / 256; i++) {
        int e = e0 + i * 256 + t;
        pd[i] = 0xFFFFFFFFu;
        if (e < N_EDGES) {
            unsigned s = (unsigned)ei[e];
            unsigned d = (unsigned)ei[N_EDGES + e];
            pd[i] = (d << 16) | s;
            loc[i] = atomicAdd(&cnt[d >> BUK_SHIFT], 1);
        }
    }
    __syncthreads();
    for (int j = t; j < NBUK; j += 256)
        base[j] = cnt[j] ? atomicAdd(&gcur[j], cnt[j]) : 0;
    __syncthreads();
#pragma unroll
    for (int i = 0; i < CHUNK_A / 256; i++) {
        if (pd[i] != 0xFFFFFFFFu) {
            unsigned d = pd[i] >> 16;
            pairs[base[d >> BUK_SHIFT] + loc[i]] =
                ((d & (BUK_SIZE - 1)) << 16) | (pd[i] & 0xFFFFu);
        }
    }
}

// ---------------- in-bucket counting sort -> CSR esrc + per-node offs ----------------
__global__ __launch_bounds__(256) void k_sort(const unsigned* __restrict__ pairs,
                                              const int* __restrict__ boffs,
                                              int* __restrict__ offs,
                                              int* __restrict__ esrc) {
    __shared__ int cnt[BUK_SIZE];
    __shared__ int sm[BUK_SIZE];
    __shared__ int cur[BUK_SIZE];
    int b = blockIdx.x, t = threadIdx.x;
    int n0 = b << BUK_SHIFT;
    int nrows = min(BUK_SIZE, N_NODES - n0);
    int e0 = boffs[b], e1 = boffs[b + 1];
    int m = e1 - e0;
    if (t < BUK_SIZE) cnt[t] = 0;
    __syncthreads();
    for (int j = t; j < m; j += 256)
        atomicAdd(&cnt[pairs[e0 + j] >> 16], 1);
    __syncthreads();
    if (t < BUK_SIZE) sm[t] = cnt[t];
    __syncthreads();
    for (int off = 1; off < BUK_SIZE; off <<= 1) {
        int v = 0, u = 0;
        if (t < BUK_SIZE) { v = sm[t]; u = (t >= off) ? sm[t - off] : 0; }
        __syncthreads();
        if (t < BUK_SIZE) sm[t] = v + u;
        __syncthreads();
    }
    if (t < BUK_SIZE) {
        int ex = sm[t] - cnt[t];
        cur[t] = ex;
        if (t < nrows) offs[n0 + t] = e0 + ex;
    }
    __syncthreads();
    for (int j = t; j < m; j += 256) {
        unsigned p = pairs[e0 + j];
        int pos = atomicAdd(&cur[p >> 16], 1);
        esrc[e0 + pos] = (int)(p & 0xFFFFu);
    }
}

// ---------------- gather-sum (float4-vectorized, 4 edge-groups/wave) ----------------
__global__ __launch_bounds__(256) void k_gather(const float* __restrict__ x,
                                                const int* __restrict__ offs,
                                                const int* __restrict__ esrc,
                                                float* __restrict__ agg) {
    int wid = (blockIdx.x * 256 + threadIdx.x) >> 6;   // wave = node
    int lane = threadIdx.x & 63;
    if (wid >= N_NODES) return;
    int grp = lane >> 4;       // edge sub-group 0..3
    int f4  = lane & 15;       // float4 slot within row
    const float4* x4 = (const float4*)x;
    int base = offs[wid], end = offs[wid + 1];
    float4 acc = make_float4(0.f, 0.f, 0.f, 0.f);
    int i = base;
    for (; i + 7 < end; i += 8) {                      // 2 independent 1KB wave-loads
        int s0 = esrc[i + grp];
        int s1 = esrc[i + 4 + grp];
        float4 v0 = x4[(size_t)s0 * 16 + f4];
        float4 v1 = x4[(size_t)s1 * 16 + f4];
        acc.x += v0.x; acc.y += v0.y; acc.z += v0.z; acc.w += v0.w;
        acc.x += v1.x; acc.y += v1.y; acc.z += v1.z; acc.w += v1.w;
    }
    for (; i + 3 < end; i += 4) {
        int s = esrc[i + grp];
        float4 v = x4[(size_t)s * 16 + f4];
        acc.x += v.x; acc.y += v.y; acc.z += v.z; acc.w += v.w;
    }
    int rem = end - i;
    if (grp < rem) {
        int s = esrc[i + grp];
        float4 v = x4[(size_t)s * 16 + f4];
        acc.x += v.x; acc.y += v.y; acc.z += v.z; acc.w += v.w;
    }
    // reduce across the 4 groups (lanes xor 16, xor 32)
    acc.x += __shfl_xor(acc.x, 16, 64); acc.y += __shfl_xor(acc.y, 16, 64);
    acc.z += __shfl_xor(acc.z, 16, 64); acc.w += __shfl_xor(acc.w, 16, 64);
    acc.x += __shfl_xor(acc.x, 32, 64); acc.y += __shfl_xor(acc.y, 32, 64);
    acc.z += __shfl_xor(acc.z, 32, 64); acc.w += __shfl_xor(acc.w, 32, 64);
    if (grp == 0) {
        float4 xn = x4[(size_t)wid * 16 + f4];
        acc.x += xn.x; acc.y += xn.y; acc.z += xn.z; acc.w += xn.w;
        ((float4*)agg)[(size_t)wid * 16 + f4] = acc;   // 16 lanes, 256B coalesced
    }
}

// ---------------- GEMM1 + fused BN partial stats ----------------
// block = 64 rows x 4 col-chunks; LDS tile [64][65]
__global__ __launch_bounds__(256) void k_gemm1(const float* __restrict__ agg,
                                               const float* __restrict__ W1,
                                               const float* __restrict__ b1,
                                               float* __restrict__ h,
                                               float* __restrict__ partial) {
    __shared__ float xs[64][65];
    __shared__ float shS[4][64], shQ[4][64];
    int blk = blockIdx.x, t = threadIdx.x;
    int r0 = blk * 64;
    const float4* a4 = (const float4*)(agg + (size_t)r0 * D);
    for (int i = t; i < 1024; i += 256) {       // coalesced 16KB tile load
        float4 v = a4[i];                        // tail block over-reads into h region (allocated)
        int row = i >> 4, q = (i & 15) * 4;
        xs[row][q] = v.x; xs[row][q + 1] = v.y;
        xs[row][q + 2] = v.z; xs[row][q + 3] = v.w;
    }
    __syncthreads();
    int lane = t & 63, chunk = t >> 6;
    int r = r0 + lane, c0 = chunk * 16;
    float acc[16];
#pragma unroll
    for (int j = 0; j < 16; j++) acc[j] = b1[c0 + j];
#pragma unroll 4
    for (int k = 0; k < D; k++) {
        float v = xs[lane][k];
#pragma unroll
        for (int j = 0; j < 16; j++)
            acc[j] += v * W1[k * D + c0 + j];    // wave-uniform -> scalar loads
    }
    if (r < N_NODES) {
        float* hp = h + (size_t)r * D + c0;
#pragma unroll
        for (int j4 = 0; j4 < 4; j4++) {
            float4 o;
            o.x = acc[j4 * 4]; o.y = acc[j4 * 4 + 1];
            o.z = acc[j4 * 4 + 2]; o.w = acc[j4 * 4 + 3];
            *(float4*)(hp + j4 * 4) = o;
        }
    }
    // ---- BN partials over this tile (pre-ReLU h) ----
    __syncthreads();                             // everyone done reading xs
#pragma unroll
    for (int j = 0; j < 16; j++) xs[lane][c0 + j] = acc[j];
    __syncthreads();
    int nval = min(64, N_NODES - r0);
    {
        float s = 0.f, q = 0.f;
        for (int rr = chunk; rr < nval; rr += 4) {
            float v = xs[rr][lane];              // stride-1 across lanes: conflict-free
            s += v; q += v * v;
        }
        shS[chunk][lane] = s; shQ[chunk][lane] = q;
    }
    __syncthreads();
    if (chunk == 0) {
        float ts = shS[0][lane] + shS[1][lane] + shS[2][lane] + shS[3][lane];
        float tq = shQ[0][lane] + shQ[1][lane] + shQ[2][lane] + shQ[3][lane];
        partial[blk * 128 + lane] = ts;
        partial[blk * 128 + 64 + lane] = tq;
    }
}

// ---------------- BN finalize: reduce 782 partials, fold gamma/beta ----------------
__global__ __launch_bounds__(512) void k_bnfinal(const float* __restrict__ partial,
                                                 const float* __restrict__ gamma,
                                                 const float* __restrict__ beta,
                                                 float* __restrict__ bnscale,
                                                 float* __restrict__ bnshift) {
    __shared__ float sh[4][128];
    int t = threadIdx.x, c = t & 127, sl = t >> 7;
    float s = 0.f;
    for (int b = sl; b < GBLK; b += 4) s += partial[b * 128 + c];
    sh[sl][c] = s;
    __syncthreads();
    if (t < 128) sh[0][t] = sh[0][t] + sh[1][t] + sh[2][t] + sh[3][t];
    __syncthreads();
    if (t < 64) {
        float mean = sh[0][t] * (1.0f / N_NODES);
        float var  = sh[0][64 + t] * (1.0f / N_NODES) - mean * mean;
        float rstd = rsqrtf(var + BN_EPS);
        float sc = gamma[t] * rstd;
        bnscale[t] = sc;
        bnshift[t] = beta[t] - mean * sc;
    }
}

// ---------------- GEMM2 + fused per-graph pooling (sum & max) ----------------
__device__ __forceinline__ int lower_bound(const int* __restrict__ b, int v) {
    int lo = 0, hi = N_NODES;
    while (lo < hi) {
        int m = (lo + hi) >> 1;
        if (b[m] < v) lo = m + 1; else hi = m;
    }
    return lo;
}

__global__ __launch_bounds__(256) void k_gemm2pool(const float* __restrict__ h,
                                                   const int* __restrict__ batch,
                                                   const float* __restrict__ bnscale,
                                                   const float* __restrict__ bnshift,
                                                   const float* __restrict__ W2,
                                                   const float* __restrict__ b2,
                                                   float* __restrict__ g) {
    __shared__ float xs[64][65];
    __shared__ float bs[64], bb[64];
    __shared__ float shS[4][64], shM[4][64];
    int blk = blockIdx.x, t = threadIdx.x;
    if (t < 64) { bs[t] = bnscale[t]; bb[t] = bnshift[t]; }
    __syncthreads();
    int r0 = blk * 64;
    const float4* a4 = (const float4*)(h + (size_t)r0 * D);
    for (int i = t; i < 1024; i += 256) {
        float4 v = a4[i];
        int row = i >> 4, q = (i & 15) * 4;
        xs[row][q]     = fmaxf(v.x * bs[q]     + bb[q],     0.0f);  // bn+relu on load
        xs[row][q + 1] = fmaxf(v.y * bs[q + 1] + bb[q + 1], 0.0f);
        xs[row][q + 2] = fmaxf(v.z * bs[q + 2] + bb[q + 2], 0.0f);
        xs[row][q + 3] = fmaxf(v.w * bs[q + 3] + bb[q + 3], 0.0f);
    }
    __syncthreads();
    int lane = t & 63, chunk = t >> 6, c0 = chunk * 16;
    float acc[16];
#pragma unroll
    for (int j = 0; j < 16; j++) acc[j] = b2[c0 + j];
#pragma unroll 4
    for (int k = 0; k < D; k++) {
        float v = xs[lane][k];
#pragma unroll
        for (int j = 0; j < 16; j++)
            acc[j] += v * W2[k * D + c0 + j];
    }
#pragma unroll
    for (int j = 0; j < 16; j++) acc[j] = fmaxf(acc[j], 0.0f);      // final relu
    // ---- write h2 tile back into LDS, pool per graph segment ----
    __syncthreads();
#pragma unroll
    for (int j = 0; j < 16; j++) xs[lane][c0 + j] = acc[j];
    __syncthreads();
    int nval = min(64, N_NODES - r0);
    int gi0 = batch[r0];
    int gi1 = batch[r0 + nval - 1];
    for (int gi = gi0; gi <= gi1; gi++) {       // uniform loop, usually 1-2 iters
        int a = max(lower_bound(batch, gi) - r0, 0);
        int b = min(lower_bound(batch, gi + 1) - r0, nval);
        float s = 0.f, m = 0.f;
        for (int rr = a + chunk; rr < b; rr += 4) {
            float v = xs[rr][lane];
            s += v; m = fmaxf(m, v);
        }
        shS[chunk][lane] = s; shM[chunk][lane] = m;
        __syncthreads();
        if (chunk == 0 && b > a) {
            float ts = shS[0][lane] + shS[1][lane] + shS[2][lane] + shS[3][lane];
            float tm = fmaxf(fmaxf(shM[0][lane], shM[1][lane]),
                             fmaxf(shM[2][lane], shM[3][lane]));
            atomicAdd(&g[gi * 128 + lane], ts);
            // post-ReLU values >= 0: int compare == float compare
            atomicMax((int*)&g[gi * 128 + 64 + lane], __float_as_int(tm));
        }
        __syncthreads();
    }
}

// ---------------- head ----------------
__global__ __launch_bounds__(128) void k_head(const float* __restrict__ g,
                                              const float* __restrict__ Wl1,
                                              const float* __restrict__ bl1,
                                              const float* __restrict__ Wl2,
                                              const float* __restrict__ bl2,
                                              float* __restrict__ out) {
    __shared__ float gv[128];
    __shared__ float red[2];
    int gi = blockIdx.x;
    int t = threadIdx.x;
    gv[t] = g[gi * 128 + t];
    __syncthreads();
    float acc = bl1[t];
#pragma unroll
    for (int k = 0; k < 128; k++)
        acc += gv[k] * Wl1[k * 128 + t];
    acc = fmaxf(acc, 0.0f);
    float part = acc * Wl2[t];
    for (int off = 32; off; off >>= 1) part += __shfl_down(part, off);
    if ((t & 63) == 0) red[t >> 6] = part;
    __syncthreads();
    if (t == 0) {
        float logit = red[0] + red[1] + bl2[0];
        out[gi] = 1.0f / (1.0f + expf(-logit));
        out[NUM_GRAPHS + gi] = logit;
    }
}

extern "C" void kernel_launch(void* const* d_in, const int* in_sizes, int n_in,
                              void* d_out, int out_size, void* d_ws, size_t ws_size,
                              hipStream_t stream) {
    const float* x     = (const float*)d_in[0];
    const int*   ei    = (const int*)d_in[1];
    const int*   batch = (const int*)d_in[2];
    const float* W1    = (const float*)d_in[3];
    const float* b1    = (const float*)d_in[4];
    const float* gamma = (const float*)d_in[5];
    const float* beta  = (const float*)d_in[6];
    const float* W2    = (const float*)d_in[7];
    const float* b2    = (const float*)d_in[8];
    const float* Wl1   = (const float*)d_in[9];
    const float* bl1   = (const float*)d_in[10];
    const float* Wl2   = (const float*)d_in[11];
    const float* bl2   = (const float*)d_in[12];
    float* out = (float*)d_out;

    float* ws = (float*)d_ws;
    float* agg    = ws;                          // [N][64] row-major
    float* h      = agg + (size_t)N_NODES * D;   // [N][64] row-major
    float* gbuf   = h + (size_t)N_NODES * D;     // [512][128]  (sum | max)
    float* bnscale= gbuf + NUM_GRAPHS * 128;     // 64
    float* bnshift= bnscale + 64;                // 64
    int*   bcnt   = (int*)(bnshift + 64);        // [NBUK]
    int*   boffs  = bcnt + NBUK;                 // [NBUK+1]
    int*   gcur   = boffs + NBUK + 1;            // [NBUK]
    int*   offs   = gcur + NBUK;                 // [N+1]
    int*   esrc   = offs + N_NODES + 1;          // [E]
    float* partial= (float*)(esrc + N_EDGES);    // [GBLK*128]
    unsigned* pairs = (unsigned*)h;              // alias: pairs dead before gemm1 writes h

    hipMemsetAsync(bcnt, 0, NBUK * sizeof(int), stream);
    hipMemsetAsync(gbuf, 0, NUM_GRAPHS * 128 * sizeof(float), stream);
    k_bhist    <<<NBLK_A, 256, 0, stream>>>(ei, bcnt);
    k_bscan    <<<1, 512, 0, stream>>>(bcnt, boffs, gcur, offs);
    k_binA     <<<NBLK_A, 256, 0, stream>>>(ei, gcur, pairs);
    k_sort     <<<NBUK, 256, 0, stream>>>(pairs, boffs, offs, esrc);
    k_gather   <<<(N_NODES * 64 + 255) / 256, 256, 0, stream>>>(x, offs, esrc, agg);
    k_gemm1    <<<GBLK, 256, 0, stream>>>(agg, W1, b1, h, partial);
    k_bnfinal  <<<1, 512, 0, stream>>>(partial, gamma, beta, bnscale, bnshift);
    k_gemm2pool<<<GBLK, 256, 0, stream>>>(h, batch, bnscale, bnshift, W2, b2, gbuf);
    k_head     <<<NUM_GRAPHS, 128, 0, stream>>>(gbuf, Wl1, bl1, Wl2, bl2, out);
}

// Round 13
// 240.393 us; speedup vs baseline: 1.1732x; 1.1732x over previous
//
#include <hip/hip_runtime.h>
#include <hip/hip_bf16.h>

#define N_NODES 50000
#define N_EDGES 800000
#define NUM_GRAPHS 512
#define D 64
#define BN_EPS 1e-5f

#define BUK_SHIFT 7
#define BUK_SIZE 128
#define NBUK ((N_NODES + BUK_SIZE - 1) / BUK_SIZE)   // 391
#define CHUNK_A 4096
#define NBLK_A ((N_EDGES + CHUNK_A - 1) / CHUNK_A)   // 196
#define GBLK ((N_NODES + 63) / 64)                   // 782

// ---------------- bucket histogram (LDS-reduced) ----------------
__global__ __launch_bounds__(256) void k_bhist(const int* __restrict__ ei,
                                               int* __restrict__ bcnt) {
    __shared__ int h[NBUK];
    int t = threadIdx.x;
    for (int j = t; j < NBUK; j += 256) h[j] = 0;
    __syncthreads();
    int e0 = blockIdx.x * CHUNK_A;
#pragma unroll
    for (int i = 0; i < CHUNK_A / 256; i++) {
        int e = e0 + i * 256 + t;
        if (e < N_EDGES) atomicAdd(&h[ei[N_EDGES + e] >> BUK_SHIFT], 1);
    }
    __syncthreads();
    for (int j = t; j < NBUK; j += 256)
        if (h[j]) atomicAdd(&bcnt[j], h[j]);
}

// ---------------- exclusive scan of 391 bucket counts (+offs tail) ----------------
__global__ __launch_bounds__(512) void k_bscan(const int* __restrict__ bcnt,
                                               int* __restrict__ boffs,
                                               int* __restrict__ gcur,
                                               int* __restrict__ offs) {
    __shared__ int sm[512];
    int t = threadIdx.x;
    int v = (t < NBUK) ? bcnt[t] : 0;
    sm[t] = v;
    __syncthreads();
    for (int off = 1; off < 512; off <<= 1) {
        int a = sm[t];
        int u = (t >= off) ? sm[t - off] : 0;
        __syncthreads();
        sm[t] = a + u;
        __syncthreads();
    }
    if (t < NBUK) { int ex = sm[t] - v; boffs[t] = ex; gcur[t] = ex; }
    if (t == 0) { boffs[NBUK] = N_EDGES; offs[N_NODES] = N_EDGES; }
}

// ---------------- pass A: bin edges into buckets, packed u32 (row<<16 | src) ----------------
__global__ __launch_bounds__(256) void k_binA(const int* __restrict__ ei,
                                              int* __restrict__ gcur,
                                              unsigned* __restrict__ pairs) {
    __shared__ int cnt[NBUK];
    __shared__ int base[NBUK];
    int t = threadIdx.x;
    for (int j = t; j < NBUK; j += 256) cnt[j] = 0;
    __syncthreads();
    int e0 = blockIdx.x * CHUNK_A;
    unsigned pd[CHUNK_A / 256];
    int loc[CHUNK_A / 256];
#pragma unroll
    for (int i = 0; i < CHUNK_A / 256; i++) {
        int e = e0 + i * 256 + t;
        pd[i] = 0xFFFFFFFFu;
        if (e < N_EDGES) {
            unsigned s = (unsigned)ei[e];
            unsigned d = (unsigned)ei[N_EDGES + e];
            pd[i] = (d << 16) | s;
            loc[i] = atomicAdd(&cnt[d >> BUK_SHIFT], 1);
        }
    }
    __syncthreads();
    for (int j = t; j < NBUK; j += 256)
        base[j] = cnt[j] ? atomicAdd(&gcur[j], cnt[j]) : 0;
    __syncthreads();
#pragma unroll
    for (int i = 0; i < CHUNK_A / 256; i++) {
        if (pd[i] != 0xFFFFFFFFu) {
            unsigned d = pd[i] >> 16;
            pairs[base[d >> BUK_SHIFT] + loc[i]] =
                ((d & (BUK_SIZE - 1)) << 16) | (pd[i] & 0xFFFFu);
        }
    }
}

// ---------------- in-bucket counting sort -> CSR esrc + per-node offs ----------------
__global__ __launch_bounds__(256) void k_sort(const unsigned* __restrict__ pairs,
                                              const int* __restrict__ boffs,
                                              int* __restrict__ offs,
                                              int* __restrict__ esrc) {
    __shared__ int cnt[BUK_SIZE];
    __shared__ int sm[BUK_SIZE];
    __shared__ int cur[BUK_SIZE];
    int b = blockIdx.x, t = threadIdx.x;
    int n0 = b << BUK_SHIFT;
    int nrows = min(BUK_SIZE, N_NODES - n0);
    int e0 = boffs[b], e1 = boffs[b + 1];
    int m = e1 - e0;
    if (t < BUK_SIZE) cnt[t] = 0;
    __syncthreads();
    for (int j = t; j < m; j += 256)
        atomicAdd(&cnt[pairs[e0 + j] >> 16], 1);
    __syncthreads();
    if (t < BUK_SIZE) sm[t] = cnt[t];
    __syncthreads();
    for (int off = 1; off < BUK_SIZE; off <<= 1) {
        int v = 0, u = 0;
        if (t < BUK_SIZE) { v = sm[t]; u = (t >= off) ? sm[t - off] : 0; }
        __syncthreads();
        if (t < BUK_SIZE) sm[t] = v + u;
        __syncthreads();
    }
    if (t < BUK_SIZE) {
        int ex = sm[t] - cnt[t];
        cur[t] = ex;
        if (t < nrows) offs[n0 + t] = e0 + ex;
    }
    __syncthreads();
    for (int j = t; j < m; j += 256) {
        unsigned p = pairs[e0 + j];
        int pos = atomicAdd(&cur[p >> 16], 1);
        esrc[e0 + pos] = (int)(p & 0xFFFFu);
    }
}

// ---------------- gather-sum (float4-vectorized, 4 edge-groups/wave) ----------------
__global__ __launch_bounds__(256) void k_gather(const float* __restrict__ x,
                                                const int* __restrict__ offs,
                                                const int* __restrict__ esrc,
                                                float* __restrict__ agg) {
    int wid = (blockIdx.x * 256 + threadIdx.x) >> 6;   // wave = node
    int lane = threadIdx.x & 63;
    if (wid >= N_NODES) return;
    int grp = lane >> 4;       // edge sub-group 0..3
    int f4  = lane & 15;       // float4 slot within row
    const float4* x4 = (const float4*)x;
    int base = offs[wid], end = offs[wid + 1];
    float4 acc = make_float4(0.f, 0.f, 0.f, 0.f);
    int i = base;
    for (; i + 7 < end; i += 8) {                      // 2 independent 1KB wave-loads
        int s0 = esrc[i + grp];
        int s1 = esrc[i + 4 + grp];
        float4 v0 = x4[(size_t)s0 * 16 + f4];
        float4 v1 = x4[(size_t)s1 * 16 + f4];
        acc.x += v0.x; acc.y += v0.y; acc.z += v0.z; acc.w += v0.w;
        acc.x += v1.x; acc.y += v1.y; acc.z += v1.z; acc.w += v1.w;
    }
    for (; i + 3 < end; i += 4) {
        int s = esrc[i + grp];
        float4 v = x4[(size_t)s * 16 + f4];
        acc.x += v.x; acc.y += v.y; acc.z += v.z; acc.w += v.w;
    }
    int rem = end - i;
    if (grp < rem) {
        int s = esrc[i + grp];
        float4 v = x4[(size_t)s * 16 + f4];
        acc.x += v.x; acc.y += v.y; acc.z += v.z; acc.w += v.w;
    }
    // reduce across the 4 groups (lanes xor 16, xor 32)
    acc.x += __shfl_xor(acc.x, 16, 64); acc.y += __shfl_xor(acc.y, 16, 64);
    acc.z += __shfl_xor(acc.z, 16, 64); acc.w += __shfl_xor(acc.w, 16, 64);
    acc.x += __shfl_xor(acc.x, 32, 64); acc.y += __shfl_xor(acc.y, 32, 64);
    acc.z += __shfl_xor(acc.z, 32, 64); acc.w += __shfl_xor(acc.w, 32, 64);
    if (grp == 0) {
        float4 xn = x4[(size_t)wid * 16 + f4];
        acc.x += xn.x; acc.y += xn.y; acc.z += xn.z; acc.w += xn.w;
        ((float4*)agg)[(size_t)wid * 16 + f4] = acc;   // 16 lanes, 256B coalesced
    }
}

// ---------------- GEMM1 + fused BN partial stats ----------------
// block = 64 rows x 4 col-chunks; LDS tile [64][65]
__global__ __launch_bounds__(256) void k_gemm1(const float* __restrict__ agg,
                                               const float* __restrict__ W1,
                                               const float* __restrict__ b1,
                                               float* __restrict__ h,
                                               float* __restrict__ partial) {
    __shared__ float xs[64][65];
    __shared__ float shS[4][64], shQ[4][64];
    int blk = blockIdx.x, t = threadIdx.x;
    int r0 = blk * 64;
    const float4* a4 = (const float4*)(agg + (size_t)r0 * D);
    for (int i = t; i < 1024; i += 256) {       // coalesced 16KB tile load
        float4 v = a4[i];                        // tail block over-reads into h region (allocated)
        int row = i >> 4, q = (i & 15) * 4;
        xs[row][q] = v.x; xs[row][q + 1] = v.y;
        xs[row][q + 2] = v.z; xs[row][q + 3] = v.w;
    }
    __syncthreads();
    int lane = t & 63, chunk = t >> 6;
    int r = r0 + lane, c0 = chunk * 16;
    float acc[16];
#pragma unroll
    for (int j = 0; j < 16; j++) acc[j] = b1[c0 + j];
#pragma unroll 4
    for (int k = 0; k < D; k++) {
        float v = xs[lane][k];
#pragma unroll
        for (int j = 0; j < 16; j++)
            acc[j] += v * W1[k * D + c0 + j];    // wave-uniform -> scalar loads
    }
    if (r < N_NODES) {
        float* hp = h + (size_t)r * D + c0;
#pragma unroll
        for (int j4 = 0; j4 < 4; j4++) {
            float4 o;
            o.x = acc[j4 * 4]; o.y = acc[j4 * 4 + 1];
            o.z = acc[j4 * 4 + 2]; o.w = acc[j4 * 4 + 3];
            *(float4*)(hp + j4 * 4) = o;
        }
    }
    // ---- BN partials over this tile (pre-ReLU h) ----
    __syncthreads();                             // everyone done reading xs
#pragma unroll
    for (int j = 0; j < 16; j++) xs[lane][c0 + j] = acc[j];
    __syncthreads();
    int nval = min(64, N_NODES - r0);
    {
        float s = 0.f, q = 0.f;
        for (int rr = chunk; rr < nval; rr += 4) {
            float v = xs[rr][lane];              // stride-1 across lanes: conflict-free
            s += v; q += v * v;
        }
        shS[chunk][lane] = s; shQ[chunk][lane] = q;
    }
    __syncthreads();
    if (chunk == 0) {
        float ts = shS[0][lane] + shS[1][lane] + shS[2][lane] + shS[3][lane];
        float tq = shQ[0][lane] + shQ[1][lane] + shQ[2][lane] + shQ[3][lane];
        partial[blk * 128 + lane] = ts;
        partial[blk * 128 + 64 + lane] = tq;
    }
}

// ---------------- BN reduce: one block per stat column (128 cols) ----------------
__global__ __launch_bounds__(256) void k_bnred(const float* __restrict__ partial,
                                               float* __restrict__ colsum) {
    __shared__ float sm[256];
    int c = blockIdx.x, t = threadIdx.x;
    float s = 0.f;
    for (int b = t; b < GBLK; b += 256) s += partial[b * 128 + c];
    sm[t] = s;
    __syncthreads();
    for (int off = 128; off; off >>= 1) {
        if (t < off) sm[t] += sm[t + off];
        __syncthreads();
    }
    if (t == 0) colsum[c] = sm[0];
}

// ---------------- BN fin: fold gamma/beta (tiny) ----------------
__global__ __launch_bounds__(64) void k_bnfin(const float* __restrict__ colsum,
                                              const float* __restrict__ gamma,
                                              const float* __restrict__ beta,
                                              float* __restrict__ bnscale,
                                              float* __restrict__ bnshift) {
    int t = threadIdx.x;  // 64
    float mean = colsum[t] * (1.0f / N_NODES);
    float var  = colsum[64 + t] * (1.0f / N_NODES) - mean * mean;
    float rstd = rsqrtf(var + BN_EPS);
    float sc = gamma[t] * rstd;
    bnscale[t] = sc;
    bnshift[t] = beta[t] - mean * sc;
}

// ---------------- GEMM2 + fused per-graph pooling (sum & max) ----------------
__device__ __forceinline__ int lower_bound(const int* __restrict__ b, int v) {
    int lo = 0, hi = N_NODES;
    while (lo < hi) {
        int m = (lo + hi) >> 1;
        if (b[m] < v) lo = m + 1; else hi = m;
    }
    return lo;
}

__global__ __launch_bounds__(256) void k_gemm2pool(const float* __restrict__ h,
                                                   const int* __restrict__ batch,
                                                   const float* __restrict__ bnscale,
                                                   const float* __restrict__ bnshift,
                                                   const float* __restrict__ W2,
                                                   const float* __restrict__ b2,
                                                   float* __restrict__ g) {
    __shared__ float xs[64][65];
    __shared__ float bs[64], bb[64];
    __shared__ float shS[4][64], shM[4][64];
    int blk = blockIdx.x, t = threadIdx.x;
    if (t < 64) { bs[t] = bnscale[t]; bb[t] = bnshift[t]; }
    __syncthreads();
    int r0 = blk * 64;
    const float4* a4 = (const float4*)(h + (size_t)r0 * D);
    for (int i = t; i < 1024; i += 256) {
        float4 v = a4[i];
        int row = i >> 4, q = (i & 15) * 4;
        xs[row][q]     = fmaxf(v.x * bs[q]     + bb[q],     0.0f);  // bn+relu on load
        xs[row][q + 1] = fmaxf(v.y * bs[q + 1] + bb[q + 1], 0.0f);
        xs[row][q + 2] = fmaxf(v.z * bs[q + 2] + bb[q + 2], 0.0f);
        xs[row][q + 3] = fmaxf(v.w * bs[q + 3] + bb[q + 3], 0.0f);
    }
    __syncthreads();
    int lane = t & 63, chunk = t >> 6, c0 = chunk * 16;
    float acc[16];
#pragma unroll
    for (int j = 0; j < 16; j++) acc[j] = b2[c0 + j];
#pragma unroll 4
    for (int k = 0; k < D; k++) {
        float v = xs[lane][k];
#pragma unroll
        for (int j = 0; j < 16; j++)
            acc[j] += v * W2[k * D + c0 + j];
    }
#pragma unroll
    for (int j = 0; j < 16; j++) acc[j] = fmaxf(acc[j], 0.0f);      // final relu
    // ---- write h2 tile back into LDS, pool per graph segment ----
    __syncthreads();
#pragma unroll
    for (int j = 0; j < 16; j++) xs[lane][c0 + j] = acc[j];
    __syncthreads();
    int nval = min(64, N_NODES - r0);
    int gi0 = batch[r0];
    int gi1 = batch[r0 + nval - 1];
    for (int gi = gi0; gi <= gi1; gi++) {       // uniform loop, usually 1-2 iters
        int a = max(lower_bound(batch, gi) - r0, 0);
        int b = min(lower_bound(batch, gi + 1) - r0, nval);
        float s = 0.f, m = 0.f;
        for (int rr = a + chunk; rr < b; rr += 4) {
            float v = xs[rr][lane];
            s += v; m = fmaxf(m, v);
        }
        shS[chunk][lane] = s; shM[chunk][lane] = m;
        __syncthreads();
        if (chunk == 0 && b > a) {
            float ts = shS[0][lane] + shS[1][lane] + shS[2][lane] + shS[3][lane];
            float tm = fmaxf(fmaxf(shM[0][lane], shM[1][lane]),
                             fmaxf(shM[2][lane], shM[3][lane]));
            atomicAdd(&g[gi * 128 + lane], ts);
            // post-ReLU values >= 0: int compare == float compare
            atomicMax((int*)&g[gi * 128 + 64 + lane], __float_as_int(tm));
        }
        __syncthreads();
    }
}

// ---------------- head ----------------
__global__ __launch_bounds__(128) void k_head(const float* __restrict__ g,
                                              const float* __restrict__ Wl1,
                                              const float* __restrict__ bl1,
                                              const float* __restrict__ Wl2,
                                              const float* __restrict__ bl2,
                                              float* __restrict__ out) {
    __shared__ float gv[128];
    __shared__ float red[2];
    int gi = blockIdx.x;
    int t = threadIdx.x;
    gv[t] = g[gi * 128 + t];
    __syncthreads();
    float acc = bl1[t];
#pragma unroll
    for (int k = 0; k < 128; k++)
        acc += gv[k] * Wl1[k * 128 + t];
    acc = fmaxf(acc, 0.0f);
    float part = acc * Wl2[t];
    for (int off = 32; off; off >>= 1) part += __shfl_down(part, off);
    if ((t & 63) == 0) red[t >> 6] = part;
    __syncthreads();
    if (t == 0) {
        float logit = red[0] + red[1] + bl2[0];
        out[gi] = 1.0f / (1.0f + expf(-logit));
        out[NUM_GRAPHS + gi] = logit;
    }
}

extern "C" void kernel_launch(void* const* d_in, const int* in_sizes, int n_in,
                              void* d_out, int out_size, void* d_ws, size_t ws_size,
                              hipStream_t stream) {
    const float* x     = (const float*)d_in[0];
    const int*   ei    = (const int*)d_in[1];
    const int*   batch = (const int*)d_in[2];
    const float* W1    = (const float*)d_in[3];
    const float* b1    = (const float*)d_in[4];
    const float* gamma = (const float*)d_in[5];
    const float* beta  = (const float*)d_in[6];
    const float* W2    = (const float*)d_in[7];
    const float* b2    = (const float*)d_in[8];
    const float* Wl1   = (const float*)d_in[9];
    const float* bl1   = (const float*)d_in[10];
    const float* Wl2   = (const float*)d_in[11];
    const float* bl2   = (const float*)d_in[12];
    float* out = (float*)d_out;

    float* ws = (float*)d_ws;
    float* agg    = ws;                          // [N][64] row-major
    float* h      = agg + (size_t)N_NODES * D;   // [N][64] row-major
    float* gbuf   = h + (size_t)N_NODES * D;     // [512][128]  (sum | max)
    float* bnscale= gbuf + NUM_GRAPHS * 128;     // 64
    float* bnshift= bnscale + 64;                // 64
    float* colsum = bnshift + 64;                // 128
    int*   bcnt   = (int*)(colsum + 128);        // [NBUK]
    int*   boffs  = bcnt + NBUK;                 // [NBUK+1]
    int*   gcur   = boffs + NBUK + 1;            // [NBUK]
    int*   offs   = gcur + NBUK;                 // [N+1]
    int*   esrc   = offs + N_NODES + 1;          // [E]
    float* partial= (float*)(esrc + N_EDGES);    // [GBLK*128]
    unsigned* pairs = (unsigned*)h;              // alias: pairs dead before gemm1 writes h

    hipMemsetAsync(bcnt, 0, NBUK * sizeof(int), stream);
    hipMemsetAsync(gbuf, 0, NUM_GRAPHS * 128 * sizeof(float), stream);
    k_bhist    <<<NBLK_A, 256, 0, stream>>>(ei, bcnt);
    k_bscan    <<<1, 512, 0, stream>>>(bcnt, boffs, gcur, offs);
    k_binA     <<<NBLK_A, 256, 0, stream>>>(ei, gcur, pairs);
    k_sort     <<<NBUK, 256, 0, stream>>>(pairs, boffs, offs, esrc);
    k_gather   <<<(N_NODES * 64 + 255) / 256, 256, 0, stream>>>(x, offs, esrc, agg);
    k_gemm1    <<<GBLK, 256, 0, stream>>>(agg, W1, b1, h, partial);
    k_bnred    <<<128, 256, 0, stream>>>(partial, colsum);
    k_bnfin    <<<1, 64, 0, stream>>>(colsum, gamma, beta, bnscale, bnshift);
    k_gemm2pool<<<GBLK, 256, 0, stream>>>(h, batch, bnscale, bnshift, W2, b2, gbuf);
    k_head     <<<NUM_GRAPHS, 128, 0, stream>>>(gbuf, Wl1, bl1, Wl2, bl2, out);
}